// Round 2
// baseline (210.976 us; speedup 1.0000x reference)
//
#include <hip/hip_runtime.h>
#include <stdint.h>

#define B_ 8
#define T_ 2048
#define C_ 1024
#define H_ 64
#define M_ (B_*T_)   // 16384 rows

typedef __bf16 bf16x8 __attribute__((ext_vector_type(8)));
typedef float  f32x4  __attribute__((ext_vector_type(4)));

__device__ __forceinline__ unsigned short f32_to_bf16(float f) {
    union { float f; uint32_t u; } c; c.f = f;
    uint32_t u = c.u;
    u += 0x7fffu + ((u >> 16) & 1u);   // RNE
    return (unsigned short)(u >> 16);
}
__device__ __forceinline__ uint32_t pack2_bf16(float a, float b) {
    return (uint32_t)f32_to_bf16(a) | ((uint32_t)f32_to_bf16(b) << 16);
}

// ---------------- Kernel 1: prepack weights -> bf16 transposed [192][1024] ----
__global__ void prepack_w(const float* __restrict__ Wq, const float* __restrict__ Wk,
                          const float* __restrict__ Wv, unsigned short* __restrict__ wt) {
    int e = blockIdx.x * 256 + threadIdx.x;
    if (e >= 192 * 1024) return;
    int n = e >> 10, k = e & 1023;
    const float* W = (n < 64) ? Wq : (n < 128) ? Wk : Wv;
    wt[e] = f32_to_bf16(W[k * 64 + (n & 63)]);
}

// ---------------- Kernel 2: QKV projection (bf16 MFMA, K-chunk 64) -----------
// X[16384][1024] fp32 @ W[1024][192] -> q(scaled by 1/32),k,v bf16 [16384][64].
// 256 thr = 4 waves, 64 rows/block, grid 256. X staged via reg-prefetch; W
// B-frags read straight from global (L2-hot, 768 KB total).
__global__ __launch_bounds__(256) void qkv_kernel(const float* __restrict__ X,
        const unsigned short* __restrict__ wt,
        unsigned short* __restrict__ qb, unsigned short* __restrict__ kb,
        unsigned short* __restrict__ vb) {
    __shared__ unsigned short Xl[64][72];   // stride 72 shorts -> 2-way max (free)
    const int tid = threadIdx.x;
    const int wave = tid >> 6, lane = tid & 63;
    const int grp = lane >> 4, l15 = lane & 15;
    const int mb = blockIdx.x * 64;

    f32x4 acc[12];
    for (int i = 0; i < 12; i++) acc[i] = (f32x4){0.f, 0.f, 0.f, 0.f};

    // this thread stages row (tid>>2), 16 cols at (tid&3)*16
    const int srow = tid >> 2, scol = (tid & 3) * 16;
    const float* xp = X + (size_t)(mb + srow) * 1024 + scol;
    float4 r0 = *(const float4*)(xp + 0);
    float4 r1 = *(const float4*)(xp + 4);
    float4 r2 = *(const float4*)(xp + 8);
    float4 r3 = *(const float4*)(xp + 12);

    for (int k0 = 0; k0 < 1024; k0 += 64) {
        uint4 u0 = { pack2_bf16(r0.x, r0.y), pack2_bf16(r0.z, r0.w),
                     pack2_bf16(r1.x, r1.y), pack2_bf16(r1.z, r1.w) };
        uint4 u1 = { pack2_bf16(r2.x, r2.y), pack2_bf16(r2.z, r2.w),
                     pack2_bf16(r3.x, r3.y), pack2_bf16(r3.z, r3.w) };
        *(uint4*)&Xl[srow][scol]     = u0;
        *(uint4*)&Xl[srow][scol + 8] = u1;
        __syncthreads();
        if (k0 + 64 < 1024) {           // prefetch next chunk (overlaps MFMAs)
            const float* xn = xp + k0 + 64;
            r0 = *(const float4*)(xn + 0);
            r1 = *(const float4*)(xn + 4);
            r2 = *(const float4*)(xn + 8);
            r3 = *(const float4*)(xn + 12);
        }
        bf16x8 a0 = *(const bf16x8*)&Xl[wave * 16 + l15][grp * 8];
        bf16x8 a1 = *(const bf16x8*)&Xl[wave * 16 + l15][32 + grp * 8];
        #pragma unroll
        for (int nt = 0; nt < 12; nt++) {
            const unsigned short* wp = wt + (size_t)(nt * 16 + l15) * 1024 + k0 + grp * 8;
            bf16x8 b0 = *(const bf16x8*)wp;
            bf16x8 b1 = *(const bf16x8*)(wp + 32);
            acc[nt] = __builtin_amdgcn_mfma_f32_16x16x32_bf16(a0, b0, acc[nt], 0, 0, 0);
            acc[nt] = __builtin_amdgcn_mfma_f32_16x16x32_bf16(a1, b1, acc[nt], 0, 0, 0);
        }
        __syncthreads();
    }
    int r0q = mb + wave * 16 + grp * 4;
    #pragma unroll
    for (int nt = 0; nt < 12; nt++) {
        int col = nt * 16 + l15;
        unsigned short* dst = (col < 64) ? qb : (col < 128) ? kb : vb;
        int c = col & 63;
        float sc = (col < 64) ? 0.03125f : 1.0f;   // fold C^-0.5 into q
        for (int r = 0; r < 4; r++)
            dst[(size_t)(r0q + r) * 64 + c] = f32_to_bf16(acc[nt][r] * sc);
    }
}

// ---------------- Kernel 3: transpose V -> vt[B][64][2048] --------------------
__global__ __launch_bounds__(256) void vtrans_kernel(const unsigned short* __restrict__ vb,
                                                     unsigned short* __restrict__ vt) {
    __shared__ unsigned short tile[64][72];
    const int b = blockIdx.y, t0 = blockIdx.x * 64;
    const int tid = threadIdx.x;
    for (int i = 0; i < 2; i++) {
        int chunk = tid + 256 * i;
        int row = chunk >> 3, c8 = (chunk & 7) * 8;
        *(uint4*)&tile[row][c8] = *(const uint4*)(vb + ((size_t)(b * 2048 + t0 + row)) * 64 + c8);
    }
    __syncthreads();
    for (int i = 0; i < 2; i++) {
        int chunk = tid + 256 * i;
        int d = chunk >> 3, t8 = (chunk & 7) * 8;
        unsigned short tmp[8];
        for (int j = 0; j < 8; j++) tmp[j] = tile[t8 + j][d];
        *(uint4*)(vt + ((size_t)b * 64 + d) * 2048 + t0 + t8) = *(uint4*)tmp;
    }
}

// ---------------- Kernel 4: attention pass 1 (flash-decode) -------------------
// One wave per block: 16 q rows x one 512-key segment. 320 (qt,seg) pairs per
// batch -> grid (320, 8) = 2560 balanced blocks (<=8 key-tiles each).
// K/V fragments loaded global->reg (L2-hot); only P round-trips through LDS.
__global__ __launch_bounds__(64) void attn1_kernel(const unsigned short* __restrict__ qb,
        const unsigned short* __restrict__ kb, const unsigned short* __restrict__ vt,
        float* __restrict__ pm, float* __restrict__ pl, float* __restrict__ pacc) {
    __shared__ unsigned short Pl[16][72];
    const int lane = threadIdx.x;
    const int grp = lane >> 4, l15 = lane & 15;
    const int b = blockIdx.y;
    int f = 319 - blockIdx.x;            // heavy blocks first
    int qt, s;
    if (f < 32)       { qt = f;                 s = 0; }
    else if (f < 96)  { qt = 32 + (f - 32) / 2; s = (f - 32) % 2; }
    else if (f < 192) { qt = 64 + (f - 96) / 3; s = (f - 96) % 3; }
    else              { qt = 96 + (f - 192) / 4; s = (f - 192) % 4; }
    const int qbase = qt * 16;
    const int kstart = s * 512;
    const int kend = min(kstart + 512, qbase + 16);

    const unsigned short* qp = qb + ((size_t)b * 2048 + qbase + l15) * 64 + grp * 8;
    bf16x8 aq0 = *(const bf16x8*)qp;
    bf16x8 aq1 = *(const bf16x8*)(qp + 32);

    float m_i[4], l_i[4];
    f32x4 acc[4];
    for (int r = 0; r < 4; r++) { m_i[r] = -1e30f; l_i[r] = 0.f; }
    for (int nt = 0; nt < 4; nt++) acc[nt] = (f32x4){0.f, 0.f, 0.f, 0.f};

    for (int kbase = kstart; kbase < kend; kbase += 64) {
        // ---- S = QK^T (scale pre-folded into q) ----
        f32x4 sv[4];
        const unsigned short* kpB = kb + ((size_t)b * 2048 + kbase) * 64;
        #pragma unroll
        for (int nt = 0; nt < 4; nt++) {
            const unsigned short* kp = kpB + (nt * 16 + l15) * 64 + grp * 8;
            bf16x8 bk0 = *(const bf16x8*)kp;
            bf16x8 bk1 = *(const bf16x8*)(kp + 32);
            f32x4 t = (f32x4){0.f, 0.f, 0.f, 0.f};
            t = __builtin_amdgcn_mfma_f32_16x16x32_bf16(aq0, bk0, t, 0, 0, 0);
            t = __builtin_amdgcn_mfma_f32_16x16x32_bf16(aq1, bk1, t, 0, 0, 0);
            sv[nt] = t;
        }
        if (kbase + 63 >= qbase) {       // causal mask, diagonal tiles only
            #pragma unroll
            for (int nt = 0; nt < 4; nt++)
                for (int r = 0; r < 4; r++) {
                    int key = kbase + nt * 16 + l15;
                    int qrow = qbase + grp * 4 + r;
                    if (key > qrow) sv[nt][r] = -1e30f;
                }
        }
        // ---- online softmax ----
        float mnew[4], alpha[4];
        #pragma unroll
        for (int r = 0; r < 4; r++) {
            float rm = fmaxf(fmaxf(sv[0][r], sv[1][r]), fmaxf(sv[2][r], sv[3][r]));
            for (int off = 8; off >= 1; off >>= 1)
                rm = fmaxf(rm, __shfl_xor(rm, off, 64));
            mnew[r] = fmaxf(m_i[r], rm);
            alpha[r] = __expf(m_i[r] - mnew[r]);
            m_i[r] = mnew[r];
        }
        float rs[4] = {0.f, 0.f, 0.f, 0.f};
        unsigned short pmv[4][4];
        #pragma unroll
        for (int nt = 0; nt < 4; nt++)
            for (int r = 0; r < 4; r++) {
                float p = __expf(sv[nt][r] - mnew[r]);
                rs[r] += p;
                pmv[nt][r] = f32_to_bf16(p);
            }
        #pragma unroll
        for (int r = 0; r < 4; r++) {
            float t = rs[r];
            for (int off = 8; off >= 1; off >>= 1) t += __shfl_xor(t, off, 64);
            l_i[r] = l_i[r] * alpha[r] + t;
            for (int nt = 0; nt < 4; nt++) acc[nt][r] *= alpha[r];
        }
        // ---- P: C/D layout -> LDS -> A layout ----
        #pragma unroll
        for (int nt = 0; nt < 4; nt++)
            for (int r = 0; r < 4; r++)
                Pl[grp * 4 + r][nt * 16 + l15] = pmv[nt][r];
        __syncthreads();   // 1-wave barrier: cheap, forces lgkmcnt + cross-lane vis
        bf16x8 ap0 = *(const bf16x8*)&Pl[l15][grp * 8];
        bf16x8 ap1 = *(const bf16x8*)&Pl[l15][32 + grp * 8];
        const unsigned short* vpB = vt + (size_t)b * 64 * 2048 + kbase;
        #pragma unroll
        for (int nt = 0; nt < 4; nt++) {
            const unsigned short* vp = vpB + (size_t)(nt * 16 + l15) * 2048 + grp * 8;
            bf16x8 bv0 = *(const bf16x8*)vp;
            bf16x8 bv1 = *(const bf16x8*)(vp + 32);
            acc[nt] = __builtin_amdgcn_mfma_f32_16x16x32_bf16(ap0, bv0, acc[nt], 0, 0, 0);
            acc[nt] = __builtin_amdgcn_mfma_f32_16x16x32_bf16(ap1, bv1, acc[nt], 0, 0, 0);
        }
        __syncthreads();
    }
    // ---- write partials (m, l, unnormalized acc) ----
    #pragma unroll
    for (int r = 0; r < 4; r++) {
        size_t p = ((size_t)(b * 2048 + qbase + grp * 4 + r)) * 4 + s;
        if (l15 == 0) { pm[p] = m_i[r]; pl[p] = l_i[r]; }
        for (int nt = 0; nt < 4; nt++)
            pacc[p * 64 + nt * 16 + l15] = acc[nt][r];
    }
}

// ---------------- Kernel 5: attention pass 2 (combine segments) ---------------
__global__ __launch_bounds__(256) void attn2_kernel(const float* __restrict__ pm,
        const float* __restrict__ pl, const float* __restrict__ pacc,
        float* __restrict__ out) {
    int idx = blockIdx.x * 256 + threadIdx.x;     // 16384*16
    int row = idx >> 4;
    int d0 = (idx & 15) * 4;
    int t = row & 2047;
    int ns = (t >> 9) + 1;                        // segments of 512 keys
    float mv[4];
    float M = -1e30f;
    for (int s = 0; s < ns; s++) { mv[s] = pm[(size_t)row * 4 + s]; M = fmaxf(M, mv[s]); }
    float den = 0.f;
    f32x4 num = (f32x4){0.f, 0.f, 0.f, 0.f};
    for (int s = 0; s < ns; s++) {
        float w = __expf(mv[s] - M);
        den += w * pl[(size_t)row * 4 + s];
        f32x4 a = *(const f32x4*)&pacc[((size_t)row * 4 + s) * 64 + d0];
        num += w * a;
    }
    float inv = 1.f / den;
    *(f32x4*)&out[(size_t)row * 64 + d0] = num * inv;
}

extern "C" void kernel_launch(void* const* d_in, const int* in_sizes, int n_in,
                              void* d_out, int out_size, void* d_ws, size_t ws_size,
                              hipStream_t stream) {
    const float* X  = (const float*)d_in[0];
    const float* Wq = (const float*)d_in[1];
    const float* Wk = (const float*)d_in[2];
    const float* Wv = (const float*)d_in[3];
    float* out = (float*)d_out;

    unsigned short* qb = (unsigned short*)d_ws;          // [16384][64] bf16 (pre-scaled)
    unsigned short* kb = qb + (size_t)M_ * 64;
    unsigned short* vb = kb + (size_t)M_ * 64;
    unsigned short* wt = vb + (size_t)M_ * 64;           // [192][1024]
    unsigned short* vt = wt + (size_t)192 * 1024;        // [8][64][2048]
    float* pm   = (float*)(vt + (size_t)B_ * 64 * 2048); // [16384][4]
    float* pl   = pm + (size_t)M_ * 4;                   // [16384][4]
    float* pacc = pl + (size_t)M_ * 4;                   // [16384][4][64]

    prepack_w<<<768, 256, 0, stream>>>(Wq, Wk, Wv, wt);
    qkv_kernel<<<256, 256, 0, stream>>>(X, wt, qb, kb, vb);
    vtrans_kernel<<<dim3(32, 8), 256, 0, stream>>>(vb, vt);
    attn1_kernel<<<dim3(320, 8), 64, 0, stream>>>(qb, kb, vt, pm, pl, pacc);
    attn2_kernel<<<1024, 256, 0, stream>>>(pm, pl, pacc, out);
}